// Round 1
// baseline (227.056 us; speedup 1.0000x reference)
//
#include <hip/hip_runtime.h>

#define B_ 64
#define C_ 3
#define H_ 384
#define W_ 384
#define HW_ (H_ * W_)

__global__ __launch_bounds__(256) void affine_sample_kernel(
    const float* __restrict__ imgs,
    const float* __restrict__ theta,
    float* __restrict__ out)
{
    int idx = blockIdx.x * 256 + threadIdx.x;   // over B*H*W, exact multiple
    int x = idx % W_;
    int t = idx / W_;
    int y = t % H_;
    int b = t / H_;

    const float* th = theta + b * 6;
    float t00 = th[0], t01 = th[1], t02 = th[2];
    float t10 = th[3], t11 = th[4], t12 = th[5];

    float xg = (float)x - 191.5f;
    float yg = (float)y - 191.5f;

    // source coords in pixel space
    float ix = fmaf(xg, t00, fmaf(yg, t01, t02)) + 191.5f;
    float iy = fmaf(xg, t10, fmaf(yg, t11, t12)) + 191.5f;

    float x0f = floorf(ix);
    float y0f = floorf(iy);
    float wx1 = ix - x0f;
    float wy1 = iy - y0f;
    float wx0 = 1.0f - wx1;
    float wy0 = 1.0f - wy1;

    float x1f = x0f + 1.0f;
    float y1f = y0f + 1.0f;

    bool vx0 = (x0f >= 0.0f) && (x0f < (float)W_);
    bool vx1 = (x1f >= 0.0f) && (x1f < (float)W_);
    bool vy0 = (y0f >= 0.0f) && (y0f < (float)H_);
    bool vy1 = (y1f >= 0.0f) && (y1f < (float)H_);

    int x0 = (int)fminf(fmaxf(x0f, 0.0f), (float)(W_ - 1));
    int x1 = (int)fminf(fmaxf(x1f, 0.0f), (float)(W_ - 1));
    int y0 = (int)fminf(fmaxf(y0f, 0.0f), (float)(H_ - 1));
    int y1 = (int)fminf(fmaxf(y1f, 0.0f), (float)(H_ - 1));

    float w00 = wx0 * wy0 * ((vx0 && vy0) ? 1.0f : 0.0f);
    float w01 = wx1 * wy0 * ((vx1 && vy0) ? 1.0f : 0.0f);
    float w10 = wx0 * wy1 * ((vx0 && vy1) ? 1.0f : 0.0f);
    float w11 = wx1 * wy1 * ((vx1 && vy1) ? 1.0f : 0.0f);

    int o00 = y0 * W_ + x0;
    int o01 = y0 * W_ + x1;
    int o10 = y1 * W_ + x0;
    int o11 = y1 * W_ + x1;

    const float* bimg = imgs + (size_t)b * (C_ * HW_);
    float* bout = out + (size_t)b * (C_ * HW_) + y * W_ + x;

#pragma unroll
    for (int c = 0; c < C_; ++c) {
        const float* p = bimg + c * HW_;
        float v00 = p[o00];
        float v01 = p[o01];
        float v10 = p[o10];
        float v11 = p[o11];
        float r = fmaf(v00, w00, fmaf(v01, w01, fmaf(v10, w10, v11 * w11)));
        bout[c * HW_] = r;
    }
}

extern "C" void kernel_launch(void* const* d_in, const int* in_sizes, int n_in,
                              void* d_out, int out_size, void* d_ws, size_t ws_size,
                              hipStream_t stream) {
    const float* imgs = (const float*)d_in[0];
    const float* theta = (const float*)d_in[1];
    float* out = (float*)d_out;
    int total = B_ * H_ * W_;                 // 9,437,184 — exact multiple of 256
    affine_sample_kernel<<<total / 256, 256, 0, stream>>>(imgs, theta, out);
}